// Round 3
// baseline (259.253 us; speedup 1.0000x reference)
//
#include <hip/hip_runtime.h>
#include <math.h>

// Problem constants: B=2, S=2048, D=1024, H=16, dk=64
#define SB 2            // batch
#define SS 2048         // seq
#define SD 1024         // d_model
#define SH 16           // heads
#define SDK 64          // d_k
#define MROWS (SB*SS)   // 4096

typedef float  f32x4  __attribute__((ext_vector_type(4)));
typedef __bf16 bf16x8 __attribute__((ext_vector_type(8)));
typedef short  short8 __attribute__((ext_vector_type(8), may_alias));
typedef short  short4a __attribute__((ext_vector_type(4), may_alias));
typedef float  floatx4a __attribute__((ext_vector_type(4), may_alias));

__device__ __forceinline__ short f2bf(float f) {
    unsigned u = __float_as_uint(f);
    u += 0x7fffu + ((u >> 16) & 1u);          // round-to-nearest-even
    return (short)(u >> 16);
}
__device__ __forceinline__ float bf2f(short v) {
    return __uint_as_float(((unsigned)(unsigned short)v) << 16);
}
__device__ __forceinline__ bf16x8 ldb(const short* p) {
    short8 v = *(const short8*)p;
    return __builtin_bit_cast(bf16x8, v);
}
__device__ __forceinline__ void gload16(const short* g, short* l) {
    __builtin_amdgcn_global_load_lds(
        (const __attribute__((address_space(1))) unsigned*)g,
        (__attribute__((address_space(3))) unsigned*)l, 16, 0, 0);
}
#define MFMA(a, b, c) __builtin_amdgcn_mfma_f32_16x16x32_bf16((a), (b), (c), 0, 0, 0)

// ---------------- f32 -> bf16 convert ----------------
__global__ __launch_bounds__(256) void f32_to_bf16(const float* __restrict__ src,
                                                   short* __restrict__ dst, int n) {
    int i = (blockIdx.x * 256 + threadIdx.x) * 4;
    if (i >= n) return;
    floatx4a v = *(const floatx4a*)(src + i);
    short4a o;
    o[0] = f2bf(v[0]); o[1] = f2bf(v[1]); o[2] = f2bf(v[2]); o[3] = f2bf(v[3]);
    *(short4a*)(dst + i) = o;
}

// ---------------- GEMM: C[M=4096,N=1024] = X @ W^T + bias ----------------
// MODE 0: write bf16 scattered to (b,h,s,d); grid.z selects (X,W,bias,out) triple
// MODE 1: write f32 row-major to OutF
template <int MODE>
__global__ __launch_bounds__(256) void gemm128(
    const short* __restrict__ X0, const short* __restrict__ X1, const short* __restrict__ X2,
    const short* __restrict__ W0, const short* __restrict__ W1, const short* __restrict__ W2,
    const float* __restrict__ bias0, const float* __restrict__ bias1, const float* __restrict__ bias2,
    short* __restrict__ O0, short* __restrict__ O1, short* __restrict__ O2,
    float* __restrict__ OutF)
{
    const int z = blockIdx.z;
    const short* X = (z == 0) ? X0 : (z == 1) ? X1 : X2;
    const short* W = (z == 0) ? W0 : (z == 1) ? W1 : W2;
    const float* Bv = (z == 0) ? bias0 : (z == 1) ? bias1 : bias2;
    short* Obf = (z == 0) ? O0 : (z == 1) ? O1 : O2;

    const int bm = blockIdx.y, bn = blockIdx.x;
    const int tid = threadIdx.x;
    const int w = tid >> 6, lane = tid & 63, g = lane >> 4, r = lane & 15;
    const int wm = w >> 1, wn = w & 1;

    __shared__ short As[128 * 32];
    __shared__ short Bsm[128 * 32];

    // staging: each thread does 2x16B for A and 2x16B for B per K-step
    const int srow = tid >> 2, sseg = tid & 3;
    const short* ga0 = X + (size_t)(bm * 128 + srow) * SD + sseg * 8;
    const short* ga1 = X + (size_t)(bm * 128 + 64 + srow) * SD + sseg * 8;
    const short* gb0 = W + (size_t)(bn * 128 + srow) * SD + sseg * 8;
    const short* gb1 = W + (size_t)(bn * 128 + 64 + srow) * SD + sseg * 8;
    short* la0 = As + tid * 8;
    short* la1 = As + 2048 + tid * 8;
    short* lb0 = Bsm + tid * 8;
    short* lb1 = Bsm + 2048 + tid * 8;

    f32x4 acc[4][4];
    const f32x4 zz = {0.f, 0.f, 0.f, 0.f};
#pragma unroll
    for (int i = 0; i < 4; i++)
#pragma unroll
        for (int j = 0; j < 4; j++) acc[i][j] = zz;

    for (int kt = 0; kt < 32; ++kt) {
        if (kt) __syncthreads();
        gload16(ga0 + kt * 32, la0);
        gload16(ga1 + kt * 32, la1);
        gload16(gb0 + kt * 32, lb0);
        gload16(gb1 + kt * 32, lb1);
        __syncthreads();   // drains vmcnt for global_load_lds + syncs waves
        bf16x8 af[4], bfr[4];
#pragma unroll
        for (int mf = 0; mf < 4; mf++) af[mf] = ldb(&As[(wm * 64 + mf * 16 + r) * 32 + g * 8]);
#pragma unroll
        for (int nf = 0; nf < 4; nf++) bfr[nf] = ldb(&Bsm[(wn * 64 + nf * 16 + r) * 32 + g * 8]);
#pragma unroll
        for (int mf = 0; mf < 4; mf++)
#pragma unroll
            for (int nf = 0; nf < 4; nf++)
                acc[mf][nf] = MFMA(af[mf], bfr[nf], acc[mf][nf]);
    }

    float bv[4];
#pragma unroll
    for (int nf = 0; nf < 4; nf++) bv[nf] = Bv[bn * 128 + wn * 64 + nf * 16 + r];

#pragma unroll
    for (int mf = 0; mf < 4; mf++)
#pragma unroll
        for (int nf = 0; nf < 4; nf++)
#pragma unroll
            for (int rr = 0; rr < 4; rr++) {
                int row = bm * 128 + wm * 64 + mf * 16 + g * 4 + rr;  // m index
                int col = bn * 128 + wn * 64 + nf * 16 + r;           // n index
                float v = acc[mf][nf][rr] + bv[nf];
                if constexpr (MODE == 0) {
                    int b = row >> 11, s = row & 2047, h = col >> 6, d = col & 63;
                    Obf[(((size_t)(b * SH + h)) * SS + s) * SDK + d] = f2bf(v);
                } else {
                    OutF[(size_t)row * SD + col] = v;
                }
            }
}

// ---------------- flash attention over (b,h, q-tile 64) ----------------
// bias[b,h] is a uniform shift of all logits in a softmax row -> softmax-invariant,
// so it is intentionally NOT applied here (it only affects mean(bias) output).
__global__ __launch_bounds__(256) void attn_flash(
    const short* __restrict__ Qb, const short* __restrict__ Kb, const short* __restrict__ Vb,
    const int* __restrict__ mask, short* __restrict__ attnb)
{
    const int blk = blockIdx.x;
    const int bh = blk >> 5, qt = blk & 31;
    const int tid = threadIdx.x;
    const int w = tid >> 6, lane = tid & 63, g = lane >> 4, r = lane & 15;

    __shared__ short Qs[64][72];   // +8 pad: breaks 128B-stride bank conflict
    __shared__ short Ks[64][72];
    __shared__ short Vts[64][72];  // V transposed: [d][key]
    __shared__ short Ps[4][16][72];

    const int srow = tid >> 2, sseg = tid & 3;
    const short* Qg = Qb + ((size_t)bh * SS + qt * 64) * SDK;
    {
        const short8* gp = (const short8*)(Qg + srow * SDK + sseg * 16);
        *(short8*)&Qs[srow][sseg * 16] = gp[0];
        *(short8*)&Qs[srow][sseg * 16 + 8] = gp[1];
    }
    __syncthreads();
    const bf16x8 qf0 = ldb(&Qs[w * 16 + r][g * 8]);
    const bf16x8 qf1 = ldb(&Qs[w * 16 + r][32 + g * 8]);

    const f32x4 zz = {0.f, 0.f, 0.f, 0.f};
    f32x4 o[4];
    float mrun[4], lrun[4];
#pragma unroll
    for (int i = 0; i < 4; i++) { o[i] = zz; mrun[i] = -1e30f; lrun[i] = 0.f; }

    const short* Kg = Kb + (size_t)bh * SS * SDK;
    const short* Vg = Vb + (size_t)bh * SS * SDK;

    for (int kt = 0; kt < 32; ++kt) {
        __syncthreads();  // prior PV reads of Ks/Vts done before overwrite
        {
            const short8* kp = (const short8*)(Kg + (size_t)(kt * 64 + srow) * SDK + sseg * 16);
            *(short8*)&Ks[srow][sseg * 16] = kp[0];
            *(short8*)&Ks[srow][sseg * 16 + 8] = kp[1];
            const short8* vp = (const short8*)(Vg + (size_t)(kt * 64 + srow) * SDK + sseg * 16);
            short8 v0 = vp[0], v1 = vp[1];
#pragma unroll
            for (int e = 0; e < 8; e++) {
                Vts[sseg * 16 + e][srow] = v0[e];
                Vts[sseg * 16 + 8 + e][srow] = v1[e];
            }
        }
        __syncthreads();

        // scores S[16 q x 64 k] per wave
        f32x4 sc[4];
#pragma unroll
        for (int nf = 0; nf < 4; nf++) {
            f32x4 s = zz;
            s = MFMA(qf0, ldb(&Ks[nf * 16 + r][g * 8]), s);
            s = MFMA(qf1, ldb(&Ks[nf * 16 + r][32 + g * 8]), s);
            sc[nf] = s;
        }
        const int col0 = kt * 64;
#pragma unroll
        for (int nf = 0; nf < 4; nf++) {
            bool dead = (mask[col0 + nf * 16 + r] == 0);
#pragma unroll
            for (int rr = 0; rr < 4; rr++) {
                float s = sc[nf][rr] * 0.125f;   // 1/sqrt(64)
                sc[nf][rr] = dead ? -1e9f : s;
            }
        }
        // online softmax (rows live on 16-lane groups)
        float pbuf[4][4];
#pragma unroll
        for (int rr = 0; rr < 4; rr++) {
            float mx = fmaxf(fmaxf(sc[0][rr], sc[1][rr]), fmaxf(sc[2][rr], sc[3][rr]));
            mx = fmaxf(mx, __shfl_xor(mx, 1));
            mx = fmaxf(mx, __shfl_xor(mx, 2));
            mx = fmaxf(mx, __shfl_xor(mx, 4));
            mx = fmaxf(mx, __shfl_xor(mx, 8));
            float mnew = fmaxf(mrun[rr], mx);
            float corr = __expf(mrun[rr] - mnew);
            mrun[rr] = mnew;
            float rs = 0.f;
#pragma unroll
            for (int nf = 0; nf < 4; nf++) {
                float p = __expf(sc[nf][rr] - mnew);
                pbuf[nf][rr] = p;
                rs += p;
            }
            rs += __shfl_xor(rs, 1); rs += __shfl_xor(rs, 2);
            rs += __shfl_xor(rs, 4); rs += __shfl_xor(rs, 8);
            lrun[rr] = lrun[rr] * corr + rs;
#pragma unroll
            for (int dn = 0; dn < 4; dn++) o[dn][rr] *= corr;
        }
        // P -> LDS (per-wave buffer), then PV
#pragma unroll
        for (int nf = 0; nf < 4; nf++)
#pragma unroll
            for (int rr = 0; rr < 4; rr++)
                Ps[w][g * 4 + rr][nf * 16 + r] = f2bf(pbuf[nf][rr]);
        __syncthreads();
#pragma unroll
        for (int kc = 0; kc < 2; kc++) {
            bf16x8 pa = ldb(&Ps[w][r][kc * 32 + g * 8]);
#pragma unroll
            for (int dn = 0; dn < 4; dn++)
                o[dn] = MFMA(pa, ldb(&Vts[dn * 16 + r][kc * 32 + g * 8]), o[dn]);
        }
    }

    const int b = bh >> 4, h = bh & 15;
#pragma unroll
    for (int rr = 0; rr < 4; rr++) {
        float inv = 1.f / lrun[rr];
        int qrow = qt * 64 + w * 16 + g * 4 + rr;
        size_t base = ((size_t)(b * SS + qrow)) * SD + h * SDK;
#pragma unroll
        for (int dn = 0; dn < 4; dn++)
            attnb[base + dn * 16 + r] = f2bf(o[dn][rr] * inv);
    }
}

// ---------------- bias path: cos(Qmean, Vmean) per (b,h), then mean ----------------
__global__ __launch_bounds__(256) void bias_cos(const short* __restrict__ Qb,
                                                const short* __restrict__ Vb,
                                                float* __restrict__ biasbuf)
{
    const int bh = blockIdx.x;
    const int t = threadIdx.x;
    const int d = t & 63, c = t >> 6;
    const short* Qp = Qb + ((size_t)bh * SS + c * 512) * SDK + d;
    const short* Vp = Vb + ((size_t)bh * SS + c * 512) * SDK + d;
    float sq = 0.f, sv = 0.f;
    for (int s = 0; s < 512; s++) { sq += bf2f(Qp[(size_t)s * SDK]); sv += bf2f(Vp[(size_t)s * SDK]); }
    __shared__ float SQ[4][64], SV[4][64];
    SQ[c][d] = sq; SV[c][d] = sv;
    __syncthreads();
    if (t < 64) {
        float qm = (SQ[0][t] + SQ[1][t] + SQ[2][t] + SQ[3][t]) * (1.f / 2048.f);
        float vm = (SV[0][t] + SV[1][t] + SV[2][t] + SV[3][t]) * (1.f / 2048.f);
        float dot = qm * vm, nq = qm * qm, nv = vm * vm;
#pragma unroll
        for (int m2 = 1; m2 < 64; m2 <<= 1) {
            dot += __shfl_xor(dot, m2);
            nq += __shfl_xor(nq, m2);
            nv += __shfl_xor(nv, m2);
        }
        if (t == 0) {
            float na = fmaxf(sqrtf(nq), 1e-8f);
            float nb = fmaxf(sqrtf(nv), 1e-8f);
            biasbuf[bh] = dot / (na * nb);
        }
    }
}

__global__ __launch_bounds__(64) void bias_mean(const float* __restrict__ biasbuf,
                                                float* __restrict__ out, int idx)
{
    int t = threadIdx.x;
    float v = (t < 32) ? biasbuf[t] : 0.f;
#pragma unroll
    for (int m2 = 1; m2 < 32; m2 <<= 1) v += __shfl_xor(v, m2);
    if (t == 0) out[idx] = v * (1.f / 32.f);
}

// ---------------- launcher ----------------
extern "C" void kernel_launch(void* const* d_in, const int* in_sizes, int n_in,
                              void* d_out, int out_size, void* d_ws, size_t ws_size,
                              hipStream_t stream)
{
    const float* q  = (const float*)d_in[0];
    const float* k  = (const float*)d_in[1];
    const float* v  = (const float*)d_in[2];
    const int* mask = (const int*)d_in[3];
    const float* Wq = (const float*)d_in[4];
    const float* bq = (const float*)d_in[5];
    const float* Wk = (const float*)d_in[6];
    const float* bk = (const float*)d_in[7];
    const float* Wv = (const float*)d_in[8];
    const float* bv = (const float*)d_in[9];
    const float* Wo = (const float*)d_in[10];
    const float* bo = (const float*)d_in[11];
    float* out = (float*)d_out;

    const size_t QKV_B = (size_t)MROWS * SD * sizeof(short);  // 8 MB
    const size_t W_B   = (size_t)SD * SD * sizeof(short);     // 2 MB
    size_t off = 0;
    char* ws = (char*)d_ws;
    auto take = [&](size_t b) { void* p = ws + off; off += (b + 255) & ~(size_t)255; return p; };

    short* qb  = (short*)take(QKV_B);
    short* kb  = (short*)take(QKV_B);
    short* vb  = (short*)take(QKV_B);
    short* wqb = (short*)take(W_B);
    short* wkb = (short*)take(W_B);
    short* wvb = (short*)take(W_B);
    short* wob = (short*)take(W_B);
    short* Qh  = (short*)take(QKV_B);   // (b,h,s,d)
    short* Kh  = (short*)take(QKV_B);
    short* Vh  = (short*)take(QKV_B);
    float* biasbuf = (float*)take(256);
    short* attnb = qb;  // reuse: qb dead after projection GEMM

    const int nQKV = MROWS * SD;   // 4194304
    const int nW   = SD * SD;      // 1048576

    f32_to_bf16<<<nQKV / 1024, 256, 0, stream>>>(q, qb, nQKV);
    f32_to_bf16<<<nQKV / 1024, 256, 0, stream>>>(k, kb, nQKV);
    f32_to_bf16<<<nQKV / 1024, 256, 0, stream>>>(v, vb, nQKV);
    f32_to_bf16<<<nW / 1024, 256, 0, stream>>>(Wq, wqb, nW);
    f32_to_bf16<<<nW / 1024, 256, 0, stream>>>(Wk, wkb, nW);
    f32_to_bf16<<<nW / 1024, 256, 0, stream>>>(Wv, wvb, nW);
    f32_to_bf16<<<nW / 1024, 256, 0, stream>>>(Wo, wob, nW);

    // Q,K,V projections (z picks which)
    gemm128<0><<<dim3(SD / 128, MROWS / 128, 3), 256, 0, stream>>>(
        qb, kb, vb, wqb, wkb, wvb, bq, bk, bv, Qh, Kh, Vh, nullptr);

    bias_cos<<<SB * SH, 256, 0, stream>>>(Qh, Vh, biasbuf);

    attn_flash<<<SB * SH * (SS / 64), 256, 0, stream>>>(Qh, Kh, Vh, mask, attnb);

    // out = attn @ Wo^T + bo  (f32 straight to d_out)
    gemm128<1><<<dim3(SD / 128, MROWS / 128, 1), 256, 0, stream>>>(
        attnb, attnb, attnb, wob, wob, wob, bo, bo, bo, nullptr, nullptr, nullptr, out);

    bias_mean<<<1, 64, 0, stream>>>(biasbuf, out, out_size - 1);
}